// Round 4
// baseline (248.055 us; speedup 1.0000x reference)
//
#include <hip/hip_runtime.h>

// x [B=8, H=224, W=224, D=8, C=8] fp32, out [8, 8, 8, 10] fp32.
// lane = w-column (55 owned + 9 halo), 2 channels/lane (float2 loads).
// Round-4 structure: rows processed in groups of 4 with ping-pong buffers:
//   - joint vertical max kills 3/4 of the prev-rotate movs
//   - next group's 8 loads issue before ~500cy of compute (4-row prefetch
//     depth; round 3's 1-row depth left waves stalled on vmcnt ~38% of time)
//   - mov_dpp (undef old) folds into v_max_f32_dpp (update_dpp with old=0
//     is not fmax-identity, so the fold was not guaranteed before)
//   - warm/tail guards are compile-time via the group-index template: the
//     row pipeline has zero branches.
#define BB 8
#define HH 224
#define WW 224
#define DCH 64
#define NS 10
#define SEG 55    // owned output columns per wave (lanes 55..63 = halo)
#define NSEG 5
#define STRIP 56  // output rows per strip
#define NHS 4     // 4*56 = 224
#define NCG 8     // 8 channel-groups of 8 ch per block (wave = 2 ch)
#define NBLK (BB * NCG * NSEG * NHS) // 1280 = 8 XCDs * 160
#define RST (WW * DCH)               // floats per input row

__global__ void zero_kernel(float* out, int n) {
    int i = blockIdx.x * blockDim.x + threadIdx.x;
    if (i < n) out[i] = 0.0f;
}

__global__ void finalize_kernel(float* out, int n) {
    int i = blockIdx.x * blockDim.x + threadIdx.x;
    if (i < n) out[i] = fmaxf(out[i], 0.0f) + 1.0f;
}

// lane i <- lane i+1 (wave_shl:1 = 0x130), lane 63 reads 0 (bound_ctrl).
// mov_dpp's implicit-undef old is the form GCNDPPCombine folds into the
// consuming v_max_f32 (verified direction: round 3 refcheck passed).
__device__ __forceinline__ float dpp_shl1(float v) {
#if defined(__has_builtin) && __has_builtin(__builtin_amdgcn_mov_dpp)
    return __int_as_float(__builtin_amdgcn_mov_dpp(__float_as_int(v), 0x130, 0xF, 0xF, true));
#else
    return __int_as_float(__builtin_amdgcn_update_dpp(0, __float_as_int(v), 0x130, 0xF, 0xF, true));
#endif
}

// Process 4 consecutive input rows (h = row0 + 4*G + i). G >= 0: guards
// constant-fold per (i, lv); G == -1: steady (all guards true).
// Guard math (verified == round-3 semantics): scale lv+2 output row
// r = h-lv-1 in-strip  <=>  lv+1 <= 4G+i <= 56+lv ; scale 1: 4G+i <= 55.
template<int G>
__device__ __forceinline__ void group4(float (&c)[4][2], float (&p)[NS - 1][2],
                                       float (&acc)[NS][2], const float (&m)[NS]) {
#pragma unroll
    for (int i = 0; i < 4; ++i)
        if (G < 0 || 4 * G + i <= 55) {
#pragma unroll
            for (int ch = 0; ch < 2; ++ch)
                acc[0][ch] = fmaf(c[i][ch], m[0], acc[0][ch]);
        }
#pragma unroll
    for (int lv = 0; lv < NS - 1; ++lv) {
        float t[4][2];
#pragma unroll
        for (int ch = 0; ch < 2; ++ch) { // joint vertical max: 1 mov per 4 rows
            t[0][ch] = fmaxf(p[lv][ch], c[0][ch]);
            t[1][ch] = fmaxf(c[0][ch], c[1][ch]);
            t[2][ch] = fmaxf(c[1][ch], c[2][ch]);
            t[3][ch] = fmaxf(c[2][ch], c[3][ch]);
            p[lv][ch] = c[3][ch];
        }
#pragma unroll
        for (int i = 0; i < 4; ++i)
#pragma unroll
            for (int ch = 0; ch < 2; ++ch) // folds to v_max_f32_dpp
                c[i][ch] = fmaxf(t[i][ch], dpp_shl1(t[i][ch]));
#pragma unroll
        for (int i = 0; i < 4; ++i)
            if (G < 0 || (4 * G + i >= lv + 1 && 4 * G + i <= 56 + lv)) {
#pragma unroll
                for (int ch = 0; ch < 2; ++ch)
                    acc[lv + 1][ch] = fmaf(c[i][ch], m[lv + 1], acc[lv + 1][ch]);
            }
    }
}

__device__ __forceinline__ void run(const float* __restrict__ px0, int R,
                                    float (&acc)[NS][2], const float (&m)[NS]) {
    const int Rm1 = R - 1; // 64 (full strip) or 55 (bottom strip)
    float p[NS - 1][2];
#pragma unroll
    for (int lv = 0; lv < NS - 1; ++lv) { p[lv][0] = 0.0f; p[lv][1] = 0.0f; }
    float cvA[4][2], cvB[4][2];

    // Row index clamped scalar-side (s_min): over-reads in the bottom strip
    // land on row Rm1 (finite, never accumulated).
#define PRE4(buf, rb)                                                      \
    {                                                                      \
        _Pragma("unroll") for (int i = 0; i < 4; ++i) {                    \
            const int rr = min((rb) + i, Rm1);                             \
            const float2 t2 = *(const float2*)(px0 + (size_t)rr * RST);    \
            buf[i][0] = t2.x; buf[i][1] = t2.y;                            \
        }                                                                  \
    }

    PRE4(cvA, 0)
    PRE4(cvB, 4)  group4<0>(cvA, p, acc, m);   // rows 0..3   (warm)
    PRE4(cvA, 8)  group4<1>(cvB, p, acc, m);   // rows 4..7   (warm)
    PRE4(cvB, 12) group4<2>(cvA, p, acc, m);   // rows 8..11  (warm)
    PRE4(cvA, 16) group4<-1>(cvB, p, acc, m);  // rows 12..15 (steady)
    for (int k = 4; k <= 12; k += 2) {         // G4..G13: rows 16..55
        PRE4(cvB, 4 * k + 4) group4<-1>(cvA, p, acc, m);
        PRE4(cvA, 4 * k + 8) group4<-1>(cvB, p, acc, m);
    }
    if (R == STRIP + NS - 1) { // full strips only: tail rows 56..64
        PRE4(cvB, 60) group4<14>(cvA, p, acc, m); // rows 56..59
        float last[2];
        { const float2 t2 = *(const float2*)(px0 + (size_t)(STRIP + 8) * RST);
          last[0] = t2.x; last[1] = t2.y; }       // row 64
        group4<15>(cvB, p, acc, m);               // rows 60..63
        // row 64: only scale NS completes in-strip (r = row0+55)
#pragma unroll
        for (int lv = 0; lv < NS - 1; ++lv)
#pragma unroll
            for (int ch = 0; ch < 2; ++ch) {
                float t = fmaxf(p[lv][ch], last[ch]);
                last[ch] = fmaxf(t, dpp_shl1(t));
            }
#pragma unroll
        for (int ch = 0; ch < 2; ++ch)
            acc[NS - 1][ch] = fmaf(last[ch], m[NS - 1], acc[NS - 1][ch]);
    }
#undef PRE4
}

__global__ __launch_bounds__(256, 5) void pool_kernel(const float* __restrict__ x,
                                                      float* __restrict__ out) {
    // Bijective XCD swizzle: 1280 = 8*160 -> XCD k owns batch k.
    const int phys = blockIdx.x;
    const int logical = (phys & 7) * (NBLK / 8) + (phys >> 3);
    const int b  = logical / (NCG * NSEG * NHS);
    const int r  = logical % (NCG * NSEG * NHS);
    const int cg = r & 7;
    const int ws = (r >> 3) % NSEG;
    const int hs = (r >> 3) / NSEG;

    const int wv   = threadIdx.x >> 6;
    const int lane = threadIdx.x & 63;
    const int ch   = cg * 8 + wv * 2;
    const int col  = ws * SEG + lane;
    const int row0 = hs * STRIP;
    const int R    = min(STRIP + NS - 1, HH - row0); // 65, or 56 (bottom)

    float acc[NS][2];
#pragma unroll
    for (int s = 0; s < NS; ++s) { acc[s][0] = 0.0f; acc[s][1] = 0.0f; }

    float m[NS]; // per-scale column-ownership mask (0/1, applied via fma)
#pragma unroll
    for (int s = 1; s <= NS; ++s)
        m[s - 1] = (lane < SEG && col <= WW - s) ? 1.0f : 0.0f;

    // Address clamp (identity for interior waves): loads always hit valid
    // memory; masked lanes' garbage stays finite so fma(g, 0, acc) is exact.
    const int colc = min(col, WW - 1);
    const float* px0 = x + ((size_t)(b * HH + row0) * WW + colc) * DCH + ch;

    run(px0, R, acc, m);

    // Wave butterfly, then lane 0 atomics 20 partials (one per scale/channel).
#pragma unroll
    for (int s = 0; s < NS; ++s)
#pragma unroll
        for (int c = 0; c < 2; ++c) {
            float v = acc[s][c];
#pragma unroll
            for (int off = 32; off > 0; off >>= 1) v += __shfl_xor(v, off);
            if (lane == 0) atomicAdd(&out[((size_t)b * DCH + ch + c) * NS + s], v);
        }
}

extern "C" void kernel_launch(void* const* d_in, const int* in_sizes, int n_in,
                              void* d_out, int out_size, void* d_ws, size_t ws_size,
                              hipStream_t stream) {
    const float* x = (const float*)d_in[0];
    float* out = (float*)d_out;
    const int nblk = (out_size + 255) / 256;
    zero_kernel<<<nblk, 256, 0, stream>>>(out, out_size);
    pool_kernel<<<NBLK, 256, 0, stream>>>(x, out);
    finalize_kernel<<<nblk, 256, 0, stream>>>(out, out_size);
}